// Round 1
// baseline (361.027 us; speedup 1.0000x reference)
//
#include <hip/hip_runtime.h>

#define NBINS   512
#define DSTR    520          // row stride (floats), 16B-aligned rows, >= 513
#define NROWS   513
#define N_NETS  131072
#define N_PINS  (N_NETS * 4)
#define N_NODES 55000

__device__ float g_dH[NROWS * DSTR];
__device__ float g_dV[NROWS * DSTR];
__device__ float g_tH[NBINS * NBINS];
__device__ float g_tV[NBINS * NBINS];
__device__ int   g_cnt[2];

__global__ void k_zero() {
    int i = blockIdx.x * blockDim.x + threadIdx.x;
    const int N = NROWS * DSTR;
    if (i < N) { g_dH[i] = 0.0f; g_dV[i] = 0.0f; }
    if (i < 2) g_cnt[i] = 0;
}

// Scatter the 16-point 2D difference of w * (ox (x) oy) for interval
// [lox,hix] x [loy,hiy]. dx has nonzeros at {xl, xl+1, xh, xh+1} with values
// {a, -alpha, beta, -b}; coincident positions (thin boxes) sum correctly.
__device__ __forceinline__ void scatter(float lox, float hix, float loy, float hiy,
                                        float wh, float wv) {
    const float B = 1.0f / 512.0f;
    int xl = min(max((int)floorf(lox * 512.0f), 0), 511);
    int xh = min(max((int)floorf(hix * 512.0f), 0), 511);
    int yl = min(max((int)floorf(loy * 512.0f), 0), 511);
    int yh = min(max((int)floorf(hiy * 512.0f), 0), 511);
    int   xi[4]  = { xl, xl + 1, xh, xh + 1 };
    float pxv[4] = { (float)(xl + 1) * B - lox,  lox - (float)xl * B,
                     hix - (float)(xh + 1) * B,  (float)xh * B - hix };
    int   yi[4]  = { yl, yl + 1, yh, yh + 1 };
    float pyv[4] = { (float)(yl + 1) * B - loy,  loy - (float)yl * B,
                     hiy - (float)(yh + 1) * B,  (float)yh * B - hiy };
#pragma unroll
    for (int i = 0; i < 4; ++i) {
        int rb = xi[i] * DSTR;
        float px = pxv[i];
#pragma unroll
        for (int j = 0; j < 4; ++j) {
            float g = px * pyv[j];
            int off = rb + yi[j];
            atomicAdd(&g_dH[off], wh * g);
            atomicAdd(&g_dV[off], wv * g);
        }
    }
}

__global__ void k_nets(const float* __restrict__ pin_pos,
                       const float* __restrict__ nw,
                       const int*   __restrict__ fnp) {
    int n = blockIdx.x * blockDim.x + threadIdx.x;
    if (n >= N_NETS) return;
    int4 p = ((const int4*)fnp)[n];
    float x0 = pin_pos[p.x], x1 = pin_pos[p.y], x2 = pin_pos[p.z], x3 = pin_pos[p.w];
    float y0 = pin_pos[N_PINS + p.x], y1 = pin_pos[N_PINS + p.y];
    float y2 = pin_pos[N_PINS + p.z], y3 = pin_pos[N_PINS + p.w];
    float xmin = fminf(fminf(x0, x1), fminf(x2, x3));
    float xmax = fmaxf(fmaxf(x0, x1), fmaxf(x2, x3));
    float ymin = fminf(fminf(y0, y1), fminf(y2, y3));
    float ymax = fmaxf(fmaxf(y0, y1), fmaxf(y2, y3));
    float w  = nw[n];
    float wh = w / (ymax - ymin);
    float wv = w / (xmax - xmin);
    scatter(xmin, xmax, ymin, ymax, wh, wv);
}

__global__ void k_macros(const float* __restrict__ pos,
                         const float* __restrict__ nsx,
                         const float* __restrict__ nsy,
                         const int*   __restrict__ mid, int nm) {
    int i = blockIdx.x * blockDim.x + threadIdx.x;
    if (i >= nm) return;
    int idx = mid[i];
    float mx = pos[idx], my = pos[N_NODES + idx];
    float sx = nsx[idx], sy = nsy[idx];
    float wu = 10.0f / (sx * sy);   // MACRO_UTIL_H == MACRO_UTIL_V == 10
    scatter(mx, mx + sx, my, my + sy, wu, wu);
}

// Inclusive scan of each row (along y): one wave per (map,row).
__global__ void k_rowscan() {
    int bid = blockIdx.x;                       // [0,1024)
    float* D = (bid & 512) ? g_dV : g_dH;
    int row = bid & 511;
    float* base = D + row * DSTR;
    int lane = threadIdx.x;                     // 0..63, 8 elems each
    float4 a = *(float4*)(base + lane * 8);
    float4 b = *(float4*)(base + lane * 8 + 4);
    a.y += a.x; a.z += a.y; a.w += a.z;
    b.x += a.w; b.y += b.x; b.z += b.y; b.w += b.z;
    float s = b.w;
#pragma unroll
    for (int off = 1; off < 64; off <<= 1) {
        float t = __shfl_up(s, off);
        if (lane >= off) s += t;
    }
    float e = s - b.w;                          // exclusive offset
    a.x += e; a.y += e; a.z += e; a.w += e;
    b.x += e; b.y += e; b.z += e; b.w += e;
    *(float4*)(base + lane * 8)     = a;
    *(float4*)(base + lane * 8 + 4) = b;
}

// Inclusive scan down each column (along x): thread per (map,col), coalesced.
__global__ void k_colscan() {
    int t = blockIdx.x * blockDim.x + threadIdx.x;   // [0,1024)
    float* D = (t & 512) ? g_dV : g_dH;
    int col = t & 511;
    float acc = 0.0f;
#pragma unroll 8
    for (int x = 0; x < NBINS; ++x) {
        acc += D[x * DSTR + col];
        D[x * DSTR + col] = acc;
    }
}

// Blur along x (axis 0) with reflect padding, fused with normalization.
__global__ void k_blur1() {
    int t = blockIdx.x * blockDim.x + threadIdx.x;   // [0, 2*262144)
    int m = t >> 18;
    int e = t & 262143;
    int x = e >> 9, y = e & 511;
    const float* D = m ? g_dV : g_dH;
    float* T = m ? g_tV : g_tH;
    float kw = expf(-0.5f / 1024.0f);                // sigma = 32
    float k1 = 1.0f / (1.0f + 2.0f * kw);
    float k0 = kw * k1;
    const float scale = 262144.0f / 50000.0f;        // num_bins / ROUTING
    int xm = (x == 0) ? 1 : x - 1;
    int xp = (x == 511) ? 510 : x + 1;
    float v = k0 * (D[xm * DSTR + y] + D[xp * DSTR + y]) + k1 * D[x * DSTR + y];
    T[e] = v * scale;
}

// Blur along y, write map = max(|H|,|V|), wave-aggregated overflow counts.
__global__ void k_final(float* __restrict__ out) {
    int t = blockIdx.x * blockDim.x + threadIdx.x;   // [0, 262144)
    int y = t & 511;
    int ym = (y == 0) ? 1 : y - 1;
    int yp = (y == 511) ? 510 : y + 1;
    float kw = expf(-0.5f / 1024.0f);
    float k1 = 1.0f / (1.0f + 2.0f * kw);
    float k0 = kw * k1;
    int rb = t - y;
    float hb = k0 * (g_tH[rb + ym] + g_tH[rb + yp]) + k1 * g_tH[t];
    float vb = k0 * (g_tV[rb + ym] + g_tV[rb + yp]) + k1 * g_tV[t];
    out[t] = fmaxf(fabsf(hb), fabsf(vb));
    unsigned long long mh = __ballot(hb > 1.0f);
    unsigned long long mv = __ballot(vb > 1.0f);
    if ((threadIdx.x & 63) == 0) {
        atomicAdd(&g_cnt[0], (int)__popcll(mh));
        atomicAdd(&g_cnt[1], (int)__popcll(mv));
    }
}

__global__ void k_write(float* __restrict__ out) {
    int h = g_cnt[0], v = g_cnt[1];
    out[262144] = (float)((h > v) ? h : v);   // max_overflow
    out[262145] = (float)(h + v);             // total_overflow
}

extern "C" void kernel_launch(void* const* d_in, const int* in_sizes, int n_in,
                              void* d_out, int out_size, void* d_ws, size_t ws_size,
                              hipStream_t stream) {
    const float* pos     = (const float*)d_in[0];
    const float* pin_pos = (const float*)d_in[1];
    const float* nsx     = (const float*)d_in[2];
    const float* nsy     = (const float*)d_in[3];
    const float* nw      = (const float*)d_in[4];
    const int*   fnp     = (const int*)d_in[5];
    const int*   mid     = (const int*)d_in[6];
    int n_mac = in_sizes[6];
    float* out = (float*)d_out;

    hipLaunchKernelGGL(k_zero,    dim3((NROWS * DSTR + 255) / 256), dim3(256), 0, stream);
    hipLaunchKernelGGL(k_nets,    dim3(N_NETS / 256), dim3(256), 0, stream, pin_pos, nw, fnp);
    hipLaunchKernelGGL(k_macros,  dim3(1), dim3(128), 0, stream, pos, nsx, nsy, mid, n_mac);
    hipLaunchKernelGGL(k_rowscan, dim3(1024), dim3(64), 0, stream);
    hipLaunchKernelGGL(k_colscan, dim3(4), dim3(256), 0, stream);
    hipLaunchKernelGGL(k_blur1,   dim3(2048), dim3(256), 0, stream);
    hipLaunchKernelGGL(k_final,   dim3(1024), dim3(256), 0, stream, out);
    hipLaunchKernelGGL(k_write,   dim3(1), dim3(1), 0, stream, out);
}

// Round 2
// 333.886 us; speedup vs baseline: 1.0813x; 1.0813x over previous
//
#include <hip/hip_runtime.h>

#define NBINS   512
#define NROWS   513
#define DSTR2   1040         // interleaved (H,V) row stride in floats (>= 513*2)
#define N_NETS  131072
#define N_PINS  (N_NETS * 4)
#define N_NODES 55000
#define NETBLKS 4096         // N_NETS*8/256

// Interleaved difference array: g_d[x*DSTR2 + 2*y + {0:H, 1:V}]
__device__ float g_d[NROWS * DSTR2];
__device__ float g_t[NBINS * NBINS * 2];   // blurred-x, normalized, interleaved
__device__ float g_aux[16][1024];          // column chunk totals (chunk, float-col)
__device__ float g_off[16][1024];          // exclusive chunk offsets
__device__ int   g_cnt[2];

__global__ void k_zero() {
    int i = blockIdx.x * blockDim.x + threadIdx.x;
    if (i < NROWS * DSTR2) g_d[i] = 0.0f;
    if (i < 2) g_cnt[i] = 0;
}

// Full 16-point scatter (macros only — 96 threads total).
__device__ __forceinline__ void scatter16(float lox, float hix, float loy, float hiy,
                                          float wh, float wv) {
    const float B = 1.0f / 512.0f;
    int xl = min(max((int)floorf(lox * 512.0f), 0), 511);
    int xh = min(max((int)floorf(hix * 512.0f), 0), 511);
    int yl = min(max((int)floorf(loy * 512.0f), 0), 511);
    int yh = min(max((int)floorf(hiy * 512.0f), 0), 511);
    int   xi[4]  = { xl, xl + 1, xh, xh + 1 };
    float pxv[4] = { (float)(xl + 1) * B - lox,  lox - (float)xl * B,
                     hix - (float)(xh + 1) * B,  (float)xh * B - hix };
    int   yi[4]  = { yl, yl + 1, yh, yh + 1 };
    float pyv[4] = { (float)(yl + 1) * B - loy,  loy - (float)yl * B,
                     hiy - (float)(yh + 1) * B,  (float)yh * B - hiy };
#pragma unroll
    for (int i = 0; i < 4; ++i) {
#pragma unroll
        for (int j = 0; j < 4; ++j) {
            float g = pxv[i] * pyv[j];
            int off = xi[i] * DSTR2 + yi[j] * 2;
            atomicAdd(&g_d[off], wh * g);
            atomicAdd(&g_d[off + 1], wv * g);
        }
    }
}

// One thread per (net, quadrant): quadrant = (x-edge i in 0..3) x (y-pair jp in 0..1).
// 4 atomics per thread, all within one 16B span of one 32B line.
__global__ void k_nets(const float* __restrict__ pin_pos,
                       const float* __restrict__ nw,
                       const int*   __restrict__ fnp,
                       const float* __restrict__ pos,
                       const float* __restrict__ nsx,
                       const float* __restrict__ nsy,
                       const int*   __restrict__ mid, int nm) {
    if (blockIdx.x == NETBLKS) {
        int i = threadIdx.x;
        if (i >= nm) return;
        int idx = mid[i];
        float mx = pos[idx], my = pos[N_NODES + idx];
        float sx = nsx[idx], sy = nsy[idx];
        float wu = 10.0f / (sx * sy);
        scatter16(mx, mx + sx, my, my + sy, wu, wu);
        return;
    }
    int t = blockIdx.x * 256 + threadIdx.x;
    int n = t >> 3, p = t & 7;
    int4 pp = ((const int4*)fnp)[n];
    float x0 = pin_pos[pp.x], x1 = pin_pos[pp.y], x2 = pin_pos[pp.z], x3 = pin_pos[pp.w];
    float y0 = pin_pos[N_PINS + pp.x], y1 = pin_pos[N_PINS + pp.y];
    float y2 = pin_pos[N_PINS + pp.z], y3 = pin_pos[N_PINS + pp.w];
    float xmin = fminf(fminf(x0, x1), fminf(x2, x3));
    float xmax = fmaxf(fmaxf(x0, x1), fmaxf(x2, x3));
    float ymin = fminf(fminf(y0, y1), fminf(y2, y3));
    float ymax = fmaxf(fmaxf(y0, y1), fmaxf(y2, y3));
    float w  = nw[n];
    float wh = w / (ymax - ymin);
    float wv = w / (xmax - xmin);

    const float B = 1.0f / 512.0f;
    int xl = min(max((int)floorf(xmin * 512.0f), 0), 511);
    int xh = min(max((int)floorf(xmax * 512.0f), 0), 511);
    int yl = min(max((int)floorf(ymin * 512.0f), 0), 511);
    int yh = min(max((int)floorf(ymax * 512.0f), 0), 511);

    int i = p >> 1, jp = p & 1;
    int   xb = (i & 2) ? xh : xl;
    float cx = (i & 2) ? xmax : xmin;
    float ve = (float)(xb + 1) * B - cx;
    float vo = cx - (float)xb * B;
    float px = (i & 1) ? vo : ve;
    if (i & 2) px = -px;
    int xidx = xb + (i & 1);

    int   yb = jp ? yh : yl;
    float cy = jp ? ymax : ymin;
    float py0 = (float)(yb + 1) * B - cy;
    float py1 = cy - (float)yb * B;
    if (jp) { py0 = -py0; py1 = -py1; }

    float g0 = px * py0, g1 = px * py1;
    int off = xidx * DSTR2 + yb * 2;
    atomicAdd(&g_d[off + 0], wh * g0);
    atomicAdd(&g_d[off + 1], wv * g0);
    atomicAdd(&g_d[off + 2], wh * g1);
    atomicAdd(&g_d[off + 3], wv * g1);
}

// Inclusive scan of each row along y (pairs): one wave per row, 8 pairs/lane.
__global__ void k_rowscan() {
    int row = blockIdx.x;                       // [0, 512)
    float* base = g_d + row * DSTR2;
    int lane = threadIdx.x;                     // 0..63
    float4 q0 = *(float4*)(base + lane * 16);
    float4 q1 = *(float4*)(base + lane * 16 + 4);
    float4 q2 = *(float4*)(base + lane * 16 + 8);
    float4 q3 = *(float4*)(base + lane * 16 + 12);
    q0.z += q0.x; q0.w += q0.y;
    q1.x += q0.z; q1.y += q0.w; q1.z += q1.x; q1.w += q1.y;
    q2.x += q1.z; q2.y += q1.w; q2.z += q2.x; q2.w += q2.y;
    q3.x += q2.z; q3.y += q2.w; q3.z += q3.x; q3.w += q3.y;
    float sx = q3.z, sy = q3.w;
#pragma unroll
    for (int off = 1; off < 64; off <<= 1) {
        float tx = __shfl_up(sx, off);
        float ty = __shfl_up(sy, off);
        if (lane >= off) { sx += tx; sy += ty; }
    }
    float ex = sx - q3.z, ey = sy - q3.w;
    q0.x += ex; q0.y += ey; q0.z += ex; q0.w += ey;
    q1.x += ex; q1.y += ey; q1.z += ex; q1.w += ey;
    q2.x += ex; q2.y += ey; q2.z += ex; q2.w += ey;
    q3.x += ex; q3.y += ey; q3.z += ex; q3.w += ey;
    *(float4*)(base + lane * 16)      = q0;
    *(float4*)(base + lane * 16 + 4)  = q1;
    *(float4*)(base + lane * 16 + 8)  = q2;
    *(float4*)(base + lane * 16 + 12) = q3;
}

// Column scan phase 1: each thread scans a 32-row chunk of one float-column.
__global__ void k_cs1() {
    int t = blockIdx.x * 256 + threadIdx.x;     // [0, 16384)
    int c = t >> 10;                            // chunk 0..15
    int col = t & 1023;                         // float column (y*2 + map)
    float acc = 0.0f;
    int base = c * 32 * DSTR2 + col;
#pragma unroll 8
    for (int x = 0; x < 32; ++x) {
        acc += g_d[base + x * DSTR2];
        g_d[base + x * DSTR2] = acc;
    }
    g_aux[c][col] = acc;
}

// Column scan phase 2: exclusive scan of the 16 chunk totals per column.
__global__ void k_cs2() {
    int col = blockIdx.x * 256 + threadIdx.x;   // [0, 1024)
    float s = 0.0f;
#pragma unroll
    for (int c = 0; c < 16; ++c) {
        g_off[c][col] = s;
        s += g_aux[c][col];
    }
}

// Blur along x (reflect) fused with chunk-offset add + normalization.
__global__ void k_blur1() {
    int t = blockIdx.x * 256 + threadIdx.x;     // [0, 262144)
    int x = t >> 9, y = t & 511;
    int xm = (x == 0) ? 1 : x - 1;
    int xp = (x == 511) ? 510 : x + 1;
    float kw = expf(-0.5f / 1024.0f);           // sigma = 32
    float k1 = 1.0f / (1.0f + 2.0f * kw);
    float k0 = kw * k1;
    const float scale = 262144.0f / 50000.0f;
    int c0 = 2 * y, c1 = 2 * y + 1;
    float hxm = g_d[xm * DSTR2 + c0] + g_off[xm >> 5][c0];
    float vxm = g_d[xm * DSTR2 + c1] + g_off[xm >> 5][c1];
    float hxc = g_d[x  * DSTR2 + c0] + g_off[x  >> 5][c0];
    float vxc = g_d[x  * DSTR2 + c1] + g_off[x  >> 5][c1];
    float hxp = g_d[xp * DSTR2 + c0] + g_off[xp >> 5][c0];
    float vxp = g_d[xp * DSTR2 + c1] + g_off[xp >> 5][c1];
    float2 r;
    r.x = (k0 * (hxm + hxp) + k1 * hxc) * scale;
    r.y = (k0 * (vxm + vxp) + k1 * vxc) * scale;
    *(float2*)(g_t + 2 * t) = r;
}

// Blur along y, map = max(|H|,|V|), wave-aggregated overflow counts.
__global__ void k_final(float* __restrict__ out) {
    int t = blockIdx.x * 256 + threadIdx.x;     // [0, 262144)
    int y = t & 511;
    int ym = (y == 0) ? 1 : y - 1;
    int yp = (y == 511) ? 510 : y + 1;
    float kw = expf(-0.5f / 1024.0f);
    float k1 = 1.0f / (1.0f + 2.0f * kw);
    float k0 = kw * k1;
    int rb = t - y;
    float2 a = *(float2*)(g_t + 2 * (rb + ym));
    float2 b = *(float2*)(g_t + 2 * (rb + yp));
    float2 c = *(float2*)(g_t + 2 * t);
    float hb = k0 * (a.x + b.x) + k1 * c.x;
    float vb = k0 * (a.y + b.y) + k1 * c.y;
    out[t] = fmaxf(fabsf(hb), fabsf(vb));
    unsigned long long mh = __ballot(hb > 1.0f);
    unsigned long long mv = __ballot(vb > 1.0f);
    if ((threadIdx.x & 63) == 0) {
        atomicAdd(&g_cnt[0], (int)__popcll(mh));
        atomicAdd(&g_cnt[1], (int)__popcll(mv));
    }
}

__global__ void k_write(float* __restrict__ out) {
    int h = g_cnt[0], v = g_cnt[1];
    out[262144] = (float)((h > v) ? h : v);   // max_overflow
    out[262145] = (float)(h + v);             // total_overflow
}

extern "C" void kernel_launch(void* const* d_in, const int* in_sizes, int n_in,
                              void* d_out, int out_size, void* d_ws, size_t ws_size,
                              hipStream_t stream) {
    const float* pos     = (const float*)d_in[0];
    const float* pin_pos = (const float*)d_in[1];
    const float* nsx     = (const float*)d_in[2];
    const float* nsy     = (const float*)d_in[3];
    const float* nw      = (const float*)d_in[4];
    const int*   fnp     = (const int*)d_in[5];
    const int*   mid     = (const int*)d_in[6];
    int n_mac = in_sizes[6];
    float* out = (float*)d_out;

    hipLaunchKernelGGL(k_zero,    dim3((NROWS * DSTR2 + 255) / 256), dim3(256), 0, stream);
    hipLaunchKernelGGL(k_nets,    dim3(NETBLKS + 1), dim3(256), 0, stream,
                       pin_pos, nw, fnp, pos, nsx, nsy, mid, n_mac);
    hipLaunchKernelGGL(k_rowscan, dim3(512), dim3(64), 0, stream);
    hipLaunchKernelGGL(k_cs1,     dim3(64), dim3(256), 0, stream);
    hipLaunchKernelGGL(k_cs2,     dim3(4), dim3(256), 0, stream);
    hipLaunchKernelGGL(k_blur1,   dim3(1024), dim3(256), 0, stream);
    hipLaunchKernelGGL(k_final,   dim3(1024), dim3(256), 0, stream, out);
    hipLaunchKernelGGL(k_write,   dim3(1), dim3(1), 0, stream, out);
}

// Round 3
// 304.293 us; speedup vs baseline: 1.1864x; 1.0973x over previous
//
#include <hip/hip_runtime.h>

#define NBINS   512
#define DSTR2   1024         // interleaved (H,V) row stride in floats (512 cols x 2)
#define N_NETS  131072
#define N_PINS  (N_NETS * 4)
#define N_NODES 55000
#define NRECMAX (N_NETS + 128)   // nets + padded macro slots

// Difference/scan array: g_d[x*DSTR2 + 2*y + {0:H, 1:V}], x,y in [0,512)
__device__ float g_d[NBINS * DSTR2];
__device__ float g_t[NBINS * NBINS * 2];   // x-blurred, normalized, interleaved
__device__ float g_aux[16][1024];          // column chunk totals
__device__ float g_off[16][1024];          // exclusive chunk offsets
__device__ int   g_cnt[2];
// SoA bbox records (nets + macros + pad)
__device__ float g_bxl[NRECMAX], g_bxh[NRECMAX], g_byl[NRECMAX], g_byh[NRECMAX];
__device__ float g_bwh[NRECMAX], g_bwv[NRECMAX];

// Build bbox records: nets from pins, macros from pos/size, pad rejected.
__global__ void k_bbox(const float* __restrict__ pin_pos,
                       const float* __restrict__ nw,
                       const int*   __restrict__ fnp,
                       const float* __restrict__ pos,
                       const float* __restrict__ nsx,
                       const float* __restrict__ nsy,
                       const int*   __restrict__ mid, int nm) {
    int n = blockIdx.x * 256 + threadIdx.x;
    if (n >= NRECMAX) return;
    if (n < N_NETS) {
        int4 p = ((const int4*)fnp)[n];
        float x0 = pin_pos[p.x], x1 = pin_pos[p.y], x2 = pin_pos[p.z], x3 = pin_pos[p.w];
        float y0 = pin_pos[N_PINS + p.x], y1 = pin_pos[N_PINS + p.y];
        float y2 = pin_pos[N_PINS + p.z], y3 = pin_pos[N_PINS + p.w];
        float xmin = fminf(fminf(x0, x1), fminf(x2, x3));
        float xmax = fmaxf(fmaxf(x0, x1), fmaxf(x2, x3));
        float ymin = fminf(fminf(y0, y1), fminf(y2, y3));
        float ymax = fmaxf(fmaxf(y0, y1), fmaxf(y2, y3));
        float w = nw[n];
        g_bxl[n] = xmin; g_bxh[n] = xmax; g_byl[n] = ymin; g_byh[n] = ymax;
        g_bwh[n] = w / (ymax - ymin);
        g_bwv[n] = w / (xmax - xmin);
    } else if (n < N_NETS + nm) {
        int idx = mid[n - N_NETS];
        float mx = pos[idx], my = pos[N_NODES + idx];
        float sx = nsx[idx], sy = nsy[idx];
        float wu = 10.0f / (sx * sy);          // MACRO_UTIL_H == MACRO_UTIL_V
        g_bxl[n] = mx; g_bxh[n] = mx + sx; g_byl[n] = my; g_byh[n] = my + sy;
        g_bwh[n] = wu; g_bwv[n] = wu;
    } else {
        g_bxl[n] = 2.0f; g_bxh[n] = 2.0f; g_byl[n] = 0.0f; g_byh[n] = 0.0f;
        g_bwh[n] = 0.0f; g_bwv[n] = 0.0f;      // zero weight -> no-op
    }
}

// One block per 8-row x-slab: scan all records, LDS-accumulate the 16-point
// 2D-difference contributions that land in this slab, then y-prefix-scan each
// row in LDS and write the slab's rows exclusively (no global atomics).
__global__ __launch_bounds__(1024) void k_gather() {
    __shared__ float tile[8 * DSTR2];          // 32 KB: [row][2*col+map]
    int tid = threadIdx.x;
    int rowlo = blockIdx.x * 8;                // slab rows: rowlo..rowlo+7
#pragma unroll
    for (int k = 0; k < 8; ++k) tile[tid + k * 1024] = 0.0f;
    __syncthreads();

    const float B = 1.0f / 512.0f;
    for (int i = tid; i < NRECMAX; i += 1024) {
        float xmin = g_bxl[i], xmax = g_bxh[i];
        int xl = min(max((int)(xmin * 512.0f), 0), 511);
        int xh = min(max((int)(xmax * 512.0f), 0), 511);
        if (xh + 1 < rowlo || xl > rowlo + 7) continue;   // slab rejection
        float ymin = g_byl[i], ymax = g_byh[i];
        float wh = g_bwh[i], wv = g_bwv[i];
        int yl = min(max((int)(ymin * 512.0f), 0), 511);
        int yh = min(max((int)(ymax * 512.0f), 0), 511);
        int   yc[4]  = { yl, yl + 1, yh, yh + 1 };
        float pys[4] = { (float)(yl + 1) * B - ymin,  ymin - (float)yl * B,
                         ymax - (float)(yh + 1) * B,  (float)yh * B - ymax };
        int   xr[4]  = { xl, xl + 1, xh, xh + 1 };
        float pxv[4] = { (float)(xl + 1) * B - xmin,  xmin - (float)xl * B,
                         xmax - (float)(xh + 1) * B,  (float)xh * B - xmax };
#pragma unroll
        for (int e = 0; e < 4; ++e) {
            int r = xr[e] - rowlo;
            if (r < 0 || r > 7 || xr[e] > 511) continue;
            float ah = pxv[e] * wh, av = pxv[e] * wv;
#pragma unroll
            for (int j = 0; j < 4; ++j) {
                if (yc[j] > 511) continue;
                float g = pys[j];
                atomicAdd(&tile[r * 1024 + 2 * yc[j]],     ah * g);
                atomicAdd(&tile[r * 1024 + 2 * yc[j] + 1], av * g);
            }
        }
    }
    __syncthreads();

    // Fused inclusive scan along y: 16 waves <-> (8 rows x 2 maps)
    int wv_ = tid >> 6, lane = tid & 63;
    int r = wv_ >> 1, m = wv_ & 1;
    float carry = 0.0f;
#pragma unroll
    for (int ch = 0; ch < 8; ++ch) {
        int c = ch * 64 + lane;
        float v = tile[r * 1024 + 2 * c + m];
#pragma unroll
        for (int off = 1; off < 64; off <<= 1) {
            float t = __shfl_up(v, off);
            if (lane >= off) v += t;
        }
        v += carry;
        tile[r * 1024 + 2 * c + m] = v;
        carry = __shfl(v, 63);
    }
    __syncthreads();

    // Exclusive write of this slab's rows (coalesced)
#pragma unroll
    for (int k = 0; k < 8; ++k) {
        int idx = tid + k * 1024;              // 0..8191
        int rr = idx >> 10, cc = idx & 1023;
        g_d[(rowlo + rr) * DSTR2 + cc] = tile[idx];
    }
}

// Column scan phase 1: 32-row chunk partial scans (coalesced across cols).
__global__ void k_cs1() {
    int t = blockIdx.x * 256 + threadIdx.x;    // [0, 16384)
    int c = t >> 10, col = t & 1023;
    float acc = 0.0f;
    int base = c * 32 * DSTR2 + col;
#pragma unroll 8
    for (int x = 0; x < 32; ++x) {
        acc += g_d[base + x * DSTR2];
        g_d[base + x * DSTR2] = acc;
    }
    g_aux[c][col] = acc;
}

// Column scan phase 2: exclusive scan of 16 chunk totals; zero counters.
__global__ void k_cs2() {
    int col = blockIdx.x * 256 + threadIdx.x;  // [0, 1024)
    if (col < 2) g_cnt[col] = 0;
    float s = 0.0f;
#pragma unroll
    for (int c = 0; c < 16; ++c) {
        g_off[c][col] = s;
        s += g_aux[c][col];
    }
}

// Blur along x (reflect) fused with chunk-offset add + normalization.
__global__ void k_blur1() {
    int t = blockIdx.x * 256 + threadIdx.x;    // [0, 262144)
    int x = t >> 9, y = t & 511;
    int xm = (x == 0) ? 1 : x - 1;
    int xp = (x == 511) ? 510 : x + 1;
    float kw = expf(-0.5f / 1024.0f);          // sigma = 32
    float k1 = 1.0f / (1.0f + 2.0f * kw);
    float k0 = kw * k1;
    const float scale = 262144.0f / 50000.0f;
    int c0 = 2 * y, c1 = c0 + 1;
    float hxm = g_d[xm * DSTR2 + c0] + g_off[xm >> 5][c0];
    float vxm = g_d[xm * DSTR2 + c1] + g_off[xm >> 5][c1];
    float hxc = g_d[x  * DSTR2 + c0] + g_off[x  >> 5][c0];
    float vxc = g_d[x  * DSTR2 + c1] + g_off[x  >> 5][c1];
    float hxp = g_d[xp * DSTR2 + c0] + g_off[xp >> 5][c0];
    float vxp = g_d[xp * DSTR2 + c1] + g_off[xp >> 5][c1];
    float2 rr;
    rr.x = (k0 * (hxm + hxp) + k1 * hxc) * scale;
    rr.y = (k0 * (vxm + vxp) + k1 * vxc) * scale;
    *(float2*)(g_t + 2 * t) = rr;
}

// Blur along y, map = max(|H|,|V|), wave-aggregated overflow counts.
__global__ void k_final(float* __restrict__ out) {
    int t = blockIdx.x * 256 + threadIdx.x;    // [0, 262144)
    int y = t & 511;
    int ym = (y == 0) ? 1 : y - 1;
    int yp = (y == 511) ? 510 : y + 1;
    float kw = expf(-0.5f / 1024.0f);
    float k1 = 1.0f / (1.0f + 2.0f * kw);
    float k0 = kw * k1;
    int rb = t - y;
    float2 a = *(float2*)(g_t + 2 * (rb + ym));
    float2 b = *(float2*)(g_t + 2 * (rb + yp));
    float2 c = *(float2*)(g_t + 2 * t);
    float hb = k0 * (a.x + b.x) + k1 * c.x;
    float vb = k0 * (a.y + b.y) + k1 * c.y;
    out[t] = fmaxf(fabsf(hb), fabsf(vb));
    unsigned long long mh = __ballot(hb > 1.0f);
    unsigned long long mv = __ballot(vb > 1.0f);
    if ((threadIdx.x & 63) == 0) {
        atomicAdd(&g_cnt[0], (int)__popcll(mh));
        atomicAdd(&g_cnt[1], (int)__popcll(mv));
    }
}

__global__ void k_write(float* __restrict__ out) {
    int h = g_cnt[0], v = g_cnt[1];
    out[262144] = (float)((h > v) ? h : v);    // max_overflow
    out[262145] = (float)(h + v);              // total_overflow
}

extern "C" void kernel_launch(void* const* d_in, const int* in_sizes, int n_in,
                              void* d_out, int out_size, void* d_ws, size_t ws_size,
                              hipStream_t stream) {
    const float* pos     = (const float*)d_in[0];
    const float* pin_pos = (const float*)d_in[1];
    const float* nsx     = (const float*)d_in[2];
    const float* nsy     = (const float*)d_in[3];
    const float* nw      = (const float*)d_in[4];
    const int*   fnp     = (const int*)d_in[5];
    const int*   mid     = (const int*)d_in[6];
    int n_mac = in_sizes[6];
    float* out = (float*)d_out;

    hipLaunchKernelGGL(k_bbox,   dim3((NRECMAX + 255) / 256), dim3(256), 0, stream,
                       pin_pos, nw, fnp, pos, nsx, nsy, mid, n_mac);
    hipLaunchKernelGGL(k_gather, dim3(64), dim3(1024), 0, stream);
    hipLaunchKernelGGL(k_cs1,    dim3(64), dim3(256), 0, stream);
    hipLaunchKernelGGL(k_cs2,    dim3(4), dim3(256), 0, stream);
    hipLaunchKernelGGL(k_blur1,  dim3(1024), dim3(256), 0, stream);
    hipLaunchKernelGGL(k_final,  dim3(1024), dim3(256), 0, stream, out);
    hipLaunchKernelGGL(k_write,  dim3(1), dim3(1), 0, stream, out);
}

// Round 4
// 303.839 us; speedup vs baseline: 1.1882x; 1.0015x over previous
//
#include <hip/hip_runtime.h>
#include <hip/hip_cooperative_groups.h>
namespace cg = cooperative_groups;

#define N_NETS  131072
#define N_PINS  (N_NETS * 4)
#define N_NODES 55000
#define NRECPAD 135168        // 4 parts * 33792; 33792 = 33*1024
#define PARTSZ  33792

// Compact per-record scatter tables (SoA, coalesced scan on g_rows only)
__device__ uint2  g_rows[NRECPAD];     // 4 x u16 edge rows {xl, xl+1, xh, xh+1}
__device__ float  g_px  [NRECPAD * 4]; // dx values per edge
__device__ float4 g_pys [NRECPAD];     // dy values per col-edge
__device__ float2 g_whv [NRECPAD];     // (wh, wv)
__device__ uint2  g_cols[NRECPAD];     // 4 x u16 col-edges {yl, yl+1, yh, yh+1}
__device__ float  g_part[4 * 512 * 1024];  // per-part y-scanned slab tiles
__device__ float  g_dc  [512 * 1024];      // merged, chunk-scanned along x
__device__ float  g_aux [64 * 1024];       // chunk totals
__device__ float  g_offA[64 * 1024];       // exclusive chunk offsets
__device__ int    g_cnt[2];

__device__ __forceinline__ void encode(int t, float xmin, float xmax,
                                       float ymin, float ymax, float wh, float wv) {
    const float B = 1.0f / 512.0f;
    int xl = min(max((int)(xmin * 512.0f), 0), 511);
    int xh = min(max((int)(xmax * 512.0f), 0), 511);
    int yl = min(max((int)(ymin * 512.0f), 0), 511);
    int yh = min(max((int)(ymax * 512.0f), 0), 511);
    // rows/cols == 512 never match any slab / fail the c<512 test -> no sentinel needed
    g_rows[t] = make_uint2((unsigned)xl | ((unsigned)(xl + 1) << 16),
                           (unsigned)xh | ((unsigned)(xh + 1) << 16));
    float4 px;
    px.x = (xl + 1) * B - xmin;  px.y = xmin - xl * B;
    px.z = xmax - (xh + 1) * B;  px.w = xh * B - xmax;
    *(float4*)&g_px[4 * t] = px;
    g_cols[t] = make_uint2((unsigned)yl | ((unsigned)(yl + 1) << 16),
                           (unsigned)yh | ((unsigned)(yh + 1) << 16));
    float4 py;
    py.x = (yl + 1) * B - ymin;  py.y = ymin - yl * B;
    py.z = ymax - (yh + 1) * B;  py.w = yh * B - ymax;
    g_pys[t] = py;
    g_whv[t] = make_float2(wh, wv);
}

__global__ __launch_bounds__(1024, 4) void k_all(
    const float* __restrict__ pos, const float* __restrict__ pin_pos,
    const float* __restrict__ nsx, const float* __restrict__ nsy,
    const float* __restrict__ nw,  const int* __restrict__ fnp,
    const int* __restrict__ mid, int nm, float* __restrict__ out)
{
    cg::grid_group grid = cg::this_grid();
    int tid = threadIdx.x;
    int t = blockIdx.x * 1024 + tid;

    // ---- P1: bbox + compact scatter-record encode ----
    if (t < NRECPAD) {
        if (t < N_NETS) {
            int4 p = ((const int4*)fnp)[t];
            float x0 = pin_pos[p.x], x1 = pin_pos[p.y], x2 = pin_pos[p.z], x3 = pin_pos[p.w];
            float y0 = pin_pos[N_PINS + p.x], y1 = pin_pos[N_PINS + p.y];
            float y2 = pin_pos[N_PINS + p.z], y3 = pin_pos[N_PINS + p.w];
            float xmin = fminf(fminf(x0, x1), fminf(x2, x3));
            float xmax = fmaxf(fmaxf(x0, x1), fmaxf(x2, x3));
            float ymin = fminf(fminf(y0, y1), fminf(y2, y3));
            float ymax = fmaxf(fmaxf(y0, y1), fmaxf(y2, y3));
            float w = nw[t];
            encode(t, xmin, xmax, ymin, ymax, w / (ymax - ymin), w / (xmax - xmin));
        } else if (t < N_NETS + nm) {
            int idx = mid[t - N_NETS];
            float mx = pos[idx], my = pos[N_NODES + idx];
            float sx = nsx[idx], sy = nsy[idx];
            float wu = 10.0f / (sx * sy);
            encode(t, mx, mx + sx, my, my + sy, wu, wu);
        } else {
            g_rows[t] = make_uint2(~0u, ~0u);   // never matches
        }
    }
    grid.sync();

    // ---- P2: slab gather via wave-local LDS queue, y-scan, write partial ----
    {
        __shared__ float tile[8706];            // 8 rows x [H 512 | V 512] + dummies
        __shared__ unsigned q[2048];            // 16 waves x 128 entries
        int part = blockIdx.x & 3;
        unsigned rowlo = (unsigned)((blockIdx.x >> 2) * 8);
        for (int k = tid; k < 8706; k += 1024) tile[k] = 0.0f;
        __syncthreads();
        int wid = tid >> 6, lane = tid & 63;
        int wbase = wid * 128;
        unsigned long long lmask = (1ULL << lane) - 1ULL;
        int qcnt = 0;
        int pbase = part * PARTSZ;

        auto flushQ = [&](int start, int count) {
            if (lane < count) {
                unsigned ent = q[wbase + start + lane];
                int i = (int)(ent & 0x0FFFFFFFu);
                int e = (int)(ent >> 28);
                unsigned rp = ((const unsigned*)g_rows)[2 * i + (e >> 1)];
                unsigned r = (e & 1) ? (rp >> 16) : (rp & 0xFFFFu);
                int rr = (int)(r - rowlo);      // 0..7 guaranteed
                float pxv = g_px[4 * i + e];
                float2 whv = g_whv[i];
                uint2 cols = g_cols[i];
                float4 pys = g_pys[i];
                float ah = pxv * whv.x, av = pxv * whv.y;
                int base = rr * 1024;
                unsigned c0 = cols.x & 0xFFFFu, c1 = cols.x >> 16;
                unsigned c2 = cols.y & 0xFFFFu, c3 = cols.y >> 16;
                int i0 = (c0 < 512u) ? base + (int)c0 : 8192;
                int i1 = (c1 < 512u) ? base + (int)c1 : 8192;
                int i2 = (c2 < 512u) ? base + (int)c2 : 8192;
                int i3 = (c3 < 512u) ? base + (int)c3 : 8192;
                atomicAdd(&tile[i0], ah * pys.x); atomicAdd(&tile[i0 + 512], av * pys.x);
                atomicAdd(&tile[i1], ah * pys.y); atomicAdd(&tile[i1 + 512], av * pys.y);
                atomicAdd(&tile[i2], ah * pys.z); atomicAdd(&tile[i2 + 512], av * pys.z);
                atomicAdd(&tile[i3], ah * pys.w); atomicAdd(&tile[i3 + 512], av * pys.w);
            }
        };

        for (int it = 0; it < 33; ++it) {
            int i = pbase + it * 1024 + tid;
            uint2 rw = g_rows[i];
            unsigned rr4[4] = { rw.x & 0xFFFFu, rw.x >> 16, rw.y & 0xFFFFu, rw.y >> 16 };
#pragma unroll
            for (int e = 0; e < 4; ++e) {
                bool hit = (rr4[e] - rowlo) < 8u;
                unsigned long long m = __ballot(hit);
                if (hit) q[wbase + qcnt + (int)__popcll(m & lmask)] =
                             (unsigned)i | ((unsigned)e << 28);
                qcnt += (int)__popcll(m);
                if (qcnt >= 64) { qcnt -= 64; flushQ(qcnt, 64); }
            }
        }
        if (qcnt > 0) flushQ(0, qcnt);
        __syncthreads();

        // y-scan: wave wid -> (row wid>>1, map wid&1), 8 chunks of 64 with carry
        {
            int r = wid >> 1, m = wid & 1;
            int rbase = r * 1024 + m * 512;
            float carry = 0.0f;
            for (int ch = 0; ch < 8; ++ch) {
                float v = tile[rbase + ch * 64 + lane];
#pragma unroll
                for (int off = 1; off < 64; off <<= 1) {
                    float tv = __shfl_up(v, off);
                    if (lane >= off) v += tv;
                }
                v += carry;
                tile[rbase + ch * 64 + lane] = v;
                carry = __shfl(v, 63);
            }
        }
        __syncthreads();
        int dst = part * 524288 + (int)rowlo * 1024;
#pragma unroll
        for (int k = 0; k < 8; ++k) {
            int idx = tid + k * 1024;
            g_part[dst + idx] = tile[idx];
        }
    }
    grid.sync();

    // ---- P3: merge 4 parts + inclusive chunk-scan along x (8-row chunks) ----
    if (t < 65536) {
        int c = t >> 10, col = t & 1023;
        float acc = 0.0f;
        int off = (c * 8) * 1024 + col;
#pragma unroll
        for (int k = 0; k < 8; ++k) {
            float v = g_part[off] + g_part[524288 + off]
                    + g_part[2 * 524288 + off] + g_part[3 * 524288 + off];
            acc += v;
            g_dc[off] = acc;
            off += 1024;
        }
        g_aux[c * 1024 + col] = acc;
    }
    if (t < 2) g_cnt[t] = 0;
    grid.sync();

    // ---- P4: exclusive scan of 64 chunk totals per col (lane = chunk) ----
    if (t < 65536) {
        int col = t >> 6, l = t & 63;
        float v = g_aux[l * 1024 + col];
        float s = v;
#pragma unroll
        for (int off = 1; off < 64; off <<= 1) {
            float tv = __shfl_up(s, off);
            if (l >= off) s += tv;
        }
        g_offA[l * 1024 + col] = s - v;
    }
    grid.sync();

    // ---- P5+P6: blur-x (to LDS) + blur-y + map + counts; block = 2 full rows ----
    {
        __shared__ float2 sh[1024];
        int x = t >> 9, y = t & 511;
        int xm = (x == 0) ? 1 : x - 1;
        int xp = (x == 511) ? 510 : x + 1;
        float kw = expf(-0.5f / 1024.0f);       // sigma = 32
        float k1n = 1.0f / (1.0f + 2.0f * kw);
        float k0n = kw * k1n;
        const float scale = 262144.0f / 50000.0f;
        int cH = y, cV = 512 + y;
        float hxm = g_dc[xm * 1024 + cH] + g_offA[(xm >> 3) * 1024 + cH];
        float hxc = g_dc[x  * 1024 + cH] + g_offA[(x  >> 3) * 1024 + cH];
        float hxp = g_dc[xp * 1024 + cH] + g_offA[(xp >> 3) * 1024 + cH];
        float vxm = g_dc[xm * 1024 + cV] + g_offA[(xm >> 3) * 1024 + cV];
        float vxc = g_dc[x  * 1024 + cV] + g_offA[(x  >> 3) * 1024 + cV];
        float vxp = g_dc[xp * 1024 + cV] + g_offA[(xp >> 3) * 1024 + cV];
        float2 tb;
        tb.x = (k0n * (hxm + hxp) + k1n * hxc) * scale;
        tb.y = (k0n * (vxm + vxp) + k1n * vxc) * scale;
        sh[tid] = tb;
        __syncthreads();
        int ym = (y == 0) ? 1 : y - 1;
        int yp = (y == 511) ? 510 : y + 1;
        int lb = tid - y;                       // (x&1)*512
        float2 a = sh[lb + ym], b = sh[lb + yp], c = sh[tid];
        float hb = k0n * (a.x + b.x) + k1n * c.x;
        float vb = k0n * (a.y + b.y) + k1n * c.y;
        out[t] = fmaxf(fabsf(hb), fabsf(vb));
        unsigned long long mh = __ballot(hb > 1.0f);
        unsigned long long mv = __ballot(vb > 1.0f);
        if ((tid & 63) == 0) {
            atomicAdd(&g_cnt[0], (int)__popcll(mh));
            atomicAdd(&g_cnt[1], (int)__popcll(mv));
        }
    }
    grid.sync();
    if (t == 0) {
        int h = g_cnt[0], v = g_cnt[1];
        out[262144] = (float)((h > v) ? h : v);   // max_overflow
        out[262145] = (float)(h + v);             // total_overflow
    }
}

extern "C" void kernel_launch(void* const* d_in, const int* in_sizes, int n_in,
                              void* d_out, int out_size, void* d_ws, size_t ws_size,
                              hipStream_t stream) {
    const float* pos     = (const float*)d_in[0];
    const float* pin_pos = (const float*)d_in[1];
    const float* nsx     = (const float*)d_in[2];
    const float* nsy     = (const float*)d_in[3];
    const float* nw      = (const float*)d_in[4];
    const int*   fnp     = (const int*)d_in[5];
    const int*   mid     = (const int*)d_in[6];
    int nm = in_sizes[6];
    float* out = (float*)d_out;
    void* args[] = { (void*)&pos, (void*)&pin_pos, (void*)&nsx, (void*)&nsy,
                     (void*)&nw, (void*)&fnp, (void*)&mid, (void*)&nm, (void*)&out };
    hipLaunchCooperativeKernel((const void*)k_all, dim3(256), dim3(1024),
                               args, 0, stream);
}

// Round 5
// 94.553 us; speedup vs baseline: 3.8182x; 3.2134x over previous
//
#include <hip/hip_runtime.h>

#define N_NETS  131072
#define N_PINS  (N_NETS * 4)
#define N_NODES 55000
#define NPARTS  8
#define PARTSZ  17408              // 17 * 1024
#define NRECPAD (NPARTS * PARTSZ)  // 139264

// Compact per-record scatter tables (SoA)
__device__ uint2  g_rows[NRECPAD];     // 4 x u16 edge rows {xl, xl+1, xh, xh+1}
__device__ float  g_px  [NRECPAD * 4]; // dx values per edge
__device__ float4 g_pys [NRECPAD];     // dy values per col-edge
__device__ float2 g_whv [NRECPAD];     // (wh, wv)
__device__ uint2  g_cols[NRECPAD];     // 4 x u16 col-edges {yl, yl+1, yh, yh+1}
__device__ float  g_part[NPARTS * 512 * 1024];  // per-part y-scanned slab tiles
__device__ int    g_cnt[2];
__device__ int    g_tick;

__device__ __forceinline__ void encode(int t, float xmin, float xmax,
                                       float ymin, float ymax, float wh, float wv) {
    const float B = 1.0f / 512.0f;
    int xl = min(max((int)(xmin * 512.0f), 0), 511);
    int xh = min(max((int)(xmax * 512.0f), 0), 511);
    int yl = min(max((int)(ymin * 512.0f), 0), 511);
    int yh = min(max((int)(ymax * 512.0f), 0), 511);
    g_rows[t] = make_uint2((unsigned)xl | ((unsigned)(xl + 1) << 16),
                           (unsigned)xh | ((unsigned)(xh + 1) << 16));
    float4 px;
    px.x = (xl + 1) * B - xmin;  px.y = xmin - xl * B;
    px.z = xmax - (xh + 1) * B;  px.w = xh * B - xmax;
    *(float4*)&g_px[4 * t] = px;
    g_cols[t] = make_uint2((unsigned)yl | ((unsigned)(yl + 1) << 16),
                           (unsigned)yh | ((unsigned)(yh + 1) << 16));
    float4 py;
    py.x = (yl + 1) * B - ymin;  py.y = ymin - yl * B;
    py.z = ymax - (yh + 1) * B;  py.w = yh * B - ymax;
    g_pys[t] = py;
    g_whv[t] = make_float2(wh, wv);
}

__global__ __launch_bounds__(1024) void k_bbox(
    const float* __restrict__ pos, const float* __restrict__ pin_pos,
    const float* __restrict__ nsx, const float* __restrict__ nsy,
    const float* __restrict__ nw,  const int* __restrict__ fnp,
    const int* __restrict__ mid, int nm)
{
    int t = blockIdx.x * 1024 + threadIdx.x;
    if (t == 0) { g_cnt[0] = 0; g_cnt[1] = 0; g_tick = 0; }
    if (t >= NRECPAD) return;
    if (t < N_NETS) {
        int4 p = ((const int4*)fnp)[t];
        float x0 = pin_pos[p.x], x1 = pin_pos[p.y], x2 = pin_pos[p.z], x3 = pin_pos[p.w];
        float y0 = pin_pos[N_PINS + p.x], y1 = pin_pos[N_PINS + p.y];
        float y2 = pin_pos[N_PINS + p.z], y3 = pin_pos[N_PINS + p.w];
        float xmin = fminf(fminf(x0, x1), fminf(x2, x3));
        float xmax = fmaxf(fmaxf(x0, x1), fmaxf(x2, x3));
        float ymin = fminf(fminf(y0, y1), fminf(y2, y3));
        float ymax = fmaxf(fmaxf(y0, y1), fmaxf(y2, y3));
        float w = nw[t];
        encode(t, xmin, xmax, ymin, ymax, w / (ymax - ymin), w / (xmax - xmin));
    } else if (t < N_NETS + nm) {
        int idx = mid[t - N_NETS];
        float mx = pos[idx], my = pos[N_NODES + idx];
        float sx = nsx[idx], sy = nsy[idx];
        float wu = 10.0f / (sx * sy);
        encode(t, mx, mx + sx, my, my + sy, wu, wu);
    } else {
        g_rows[t] = make_uint2(~0u, ~0u);   // never matches any slab
    }
}

// 512 blocks = 8 parts x 64 slabs (8 rows each). Ballot-queue filter, native
// ds_add_f32 deposits (unsafeAtomicAdd), in-LDS y-scan, exclusive g_part write.
__global__ __launch_bounds__(1024) void k_gather() {
    __shared__ float tile[8706];            // 8 rows x [H 512 | V 512] + dummies
    __shared__ unsigned q[2048];            // 16 waves x 128 entries
    int tid = threadIdx.x;
    int part = blockIdx.x & 7;
    unsigned rowlo = (unsigned)((blockIdx.x >> 3) * 8);
#pragma unroll
    for (int k = tid; k < 8706; k += 1024) tile[k] = 0.0f;
    __syncthreads();
    int wid = tid >> 6, lane = tid & 63;
    int wbase = wid * 128;
    unsigned long long lmask = (1ULL << lane) - 1ULL;
    int qcnt = 0;
    int pbase = part * PARTSZ;

    auto flushQ = [&](int start, int count) {
        if (lane < count) {
            unsigned ent = q[wbase + start + lane];
            int i = (int)(ent & 0x0FFFFFFFu);
            int e = (int)(ent >> 28);
            unsigned rp = ((const unsigned*)g_rows)[2 * i + (e >> 1)];
            unsigned r = (e & 1) ? (rp >> 16) : (rp & 0xFFFFu);
            int rr = (int)(r - rowlo);      // 0..7 guaranteed
            float pxv = g_px[4 * i + e];
            float2 whv = g_whv[i];
            uint2 cols = g_cols[i];
            float4 pys = g_pys[i];
            float ah = pxv * whv.x, av = pxv * whv.y;
            int base = rr * 1024;
            unsigned c0 = cols.x & 0xFFFFu, c1 = cols.x >> 16;
            unsigned c2 = cols.y & 0xFFFFu, c3 = cols.y >> 16;
            int i0 = (c0 < 512u) ? base + (int)c0 : 8192;
            int i1 = (c1 < 512u) ? base + (int)c1 : 8192;
            int i2 = (c2 < 512u) ? base + (int)c2 : 8192;
            int i3 = (c3 < 512u) ? base + (int)c3 : 8192;
            unsafeAtomicAdd(&tile[i0], ah * pys.x); unsafeAtomicAdd(&tile[i0 + 512], av * pys.x);
            unsafeAtomicAdd(&tile[i1], ah * pys.y); unsafeAtomicAdd(&tile[i1 + 512], av * pys.y);
            unsafeAtomicAdd(&tile[i2], ah * pys.z); unsafeAtomicAdd(&tile[i2 + 512], av * pys.z);
            unsafeAtomicAdd(&tile[i3], ah * pys.w); unsafeAtomicAdd(&tile[i3 + 512], av * pys.w);
        }
    };

    for (int it = 0; it < 17; ++it) {
        int i = pbase + it * 1024 + tid;
        uint2 rw = g_rows[i];
        unsigned rr4[4] = { rw.x & 0xFFFFu, rw.x >> 16, rw.y & 0xFFFFu, rw.y >> 16 };
#pragma unroll
        for (int e = 0; e < 4; ++e) {
            bool hit = (rr4[e] - rowlo) < 8u;
            unsigned long long m = __ballot(hit);
            if (hit) q[wbase + qcnt + (int)__popcll(m & lmask)] =
                         (unsigned)i | ((unsigned)e << 28);
            qcnt += (int)__popcll(m);
            if (qcnt >= 64) { qcnt -= 64; flushQ(qcnt, 64); }
        }
    }
    if (qcnt > 0) flushQ(0, qcnt);
    __syncthreads();

    // y-scan: wave wid -> (row wid>>1, map wid&1), 8 chunks of 64 with carry
    {
        int r = wid >> 1, m = wid & 1;
        int rbase = r * 1024 + m * 512;
        float carry = 0.0f;
        for (int ch = 0; ch < 8; ++ch) {
            float v = tile[rbase + ch * 64 + lane];
#pragma unroll
            for (int off = 1; off < 64; off <<= 1) {
                float tv = __shfl_up(v, off);
                if (lane >= off) v += tv;
            }
            v += carry;
            tile[rbase + ch * 64 + lane] = v;
            carry = __shfl(v, 63);
        }
    }
    __syncthreads();
    int dst = part * 524288 + (int)rowlo * 1024;
#pragma unroll
    for (int k = 0; k < 8; ++k) {
        int idx = tid + k * 1024;
        g_part[dst + idx] = tile[idx];
    }
}

// 64 blocks, block b owns output cols y in [8b, 8b+8). Part-merge + y-blur
// (shfl) -> LDS; per-wave x-scan + in-register x-blur; map/counts; ticket.
__global__ __launch_bounds__(1024) void k_finish(float* __restrict__ out) {
    __shared__ float sB[16 * 512];          // [map*8+t][x], y-blurred then x-blurred
    int tid = threadIdx.x;
    int b = blockIdx.x;
    int lane = tid & 63;
    int c20 = tid & 31;                     // 0..9 H cols, 10..19 V cols
    int xg = tid >> 5;                      // 0..31
    int jj = (c20 < 10) ? c20 : c20 - 10;
    int cy = 8 * b - 1 + jj;
    if (cy < 0) cy = 1;                     // reflect pad index
    if (cy > 511) cy = 510;
    int gcol = (c20 < 10) ? cy : 512 + cy;
    const float kw  = expf(-0.5f / 1024.0f);   // sigma = 32
    const float k1n = 1.0f / (1.0f + 2.0f * kw);
    const float k0n = kw * k1n;
    const float scale = 262144.0f / 50000.0f;
    bool active = c20 < 20;
    int t8  = (c20 < 10) ? c20 - 1 : c20 - 11;
    int map = (c20 < 10) ? 0 : 1;

    for (int xo = 0; xo < 16; ++xo) {
        int x = xo * 32 + xg;
        float v = 0.0f;
        if (active) {
            int base = x * 1024 + gcol;
#pragma unroll
            for (int p = 0; p < NPARTS; ++p) v += g_part[p * 524288 + base];
        }
        float vm = __shfl(v, lane - 1);
        float vp = __shfl(v, lane + 1);
        float yb = (k0n * (vm + vp) + k1n * v) * scale;
        if (t8 >= 0 && t8 < 8) sB[(map * 8 + t8) * 512 + x] = yb;
    }
    __syncthreads();

    // x-scan: wave w owns sB row w (one (map,t) column of the die)
    int w = tid >> 6;
    float s0,s1,s2,s3,s4,s5,s6,s7;
    {
        float4 a  = *(float4*)&sB[w * 512 + lane * 8];
        float4 bq = *(float4*)&sB[w * 512 + lane * 8 + 4];
        s0 = a.x; s1 = s0 + a.y; s2 = s1 + a.z; s3 = s2 + a.w;
        s4 = s3 + bq.x; s5 = s4 + bq.y; s6 = s5 + bq.z; s7 = s6 + bq.w;
        float tot = s7;
#pragma unroll
        for (int off = 1; off < 64; off <<= 1) {
            float tv = __shfl_up(tot, off);
            if (lane >= off) tot += tv;
        }
        float e = tot - s7;
        s0 += e; s1 += e; s2 += e; s3 += e; s4 += e; s5 += e; s6 += e; s7 += e;
    }
    // x-blur in registers (reflect at x=0 -> s[1], x=511 -> s[6])
    {
        float prev = __shfl(s7, lane - 1);
        float next = __shfl(s0, lane + 1);
        float pm = (lane == 0) ? s1 : prev;
        float nx = (lane == 63) ? s6 : next;
        float b0 = k0n * (pm + s1) + k1n * s0;
        float b1 = k0n * (s0 + s2) + k1n * s1;
        float b2 = k0n * (s1 + s3) + k1n * s2;
        float b3 = k0n * (s2 + s4) + k1n * s3;
        float b4 = k0n * (s3 + s5) + k1n * s4;
        float b5 = k0n * (s4 + s6) + k1n * s5;
        float b6 = k0n * (s5 + s7) + k1n * s6;
        float b7 = k0n * (s6 + nx) + k1n * s7;
        float* row = &sB[w * 512 + lane * 8];
        row[0]=b0; row[1]=b1; row[2]=b2; row[3]=b3;
        row[4]=b4; row[5]=b5; row[6]=b6; row[7]=b7;
    }
    __syncthreads();

    // final map + counts + scalar write via ticket
    int x = tid >> 1, qh = (tid & 1) * 4;
    float4 o;
    int ch = 0, cv = 0;
#pragma unroll
    for (int k = 0; k < 4; ++k) {
        int tt = qh + k;
        float hv = sB[tt * 512 + x];
        float vv = sB[(8 + tt) * 512 + x];
        ((float*)&o)[k] = fmaxf(fabsf(hv), fabsf(vv));
        ch += (hv > 1.0f); cv += (vv > 1.0f);
    }
    *(float4*)&out[x * 512 + 8 * b + qh] = o;
#pragma unroll
    for (int off = 32; off > 0; off >>= 1) {
        ch += __shfl_down(ch, off);
        cv += __shfl_down(cv, off);
    }
    __shared__ int scnt[2];
    if (tid < 2) scnt[tid] = 0;
    __syncthreads();
    if (lane == 0) { atomicAdd(&scnt[0], ch); atomicAdd(&scnt[1], cv); }
    __syncthreads();
    if (tid == 0) {
        atomicAdd(&g_cnt[0], scnt[0]);
        atomicAdd(&g_cnt[1], scnt[1]);
        __threadfence();
        int old = atomicAdd(&g_tick, 1);
        if (old == 63) {                    // last block: all counts visible
            __threadfence();
            int h = g_cnt[0], v = g_cnt[1];
            out[262144] = (float)((h > v) ? h : v);   // max_overflow
            out[262145] = (float)(h + v);             // total_overflow
        }
    }
}

extern "C" void kernel_launch(void* const* d_in, const int* in_sizes, int n_in,
                              void* d_out, int out_size, void* d_ws, size_t ws_size,
                              hipStream_t stream) {
    const float* pos     = (const float*)d_in[0];
    const float* pin_pos = (const float*)d_in[1];
    const float* nsx     = (const float*)d_in[2];
    const float* nsy     = (const float*)d_in[3];
    const float* nw      = (const float*)d_in[4];
    const int*   fnp     = (const int*)d_in[5];
    const int*   mid     = (const int*)d_in[6];
    int nm = in_sizes[6];
    float* out = (float*)d_out;

    hipLaunchKernelGGL(k_bbox,   dim3(NRECPAD / 1024), dim3(1024), 0, stream,
                       pos, pin_pos, nsx, nsy, nw, fnp, mid, nm);
    hipLaunchKernelGGL(k_gather, dim3(512), dim3(1024), 0, stream);
    hipLaunchKernelGGL(k_finish, dim3(64), dim3(1024), 0, stream, out);
}

// Round 6
// 92.530 us; speedup vs baseline: 3.9017x; 1.0219x over previous
//
#include <hip/hip_runtime.h>

#define N_NETS  131072
#define N_PINS  (N_NETS * 4)
#define N_NODES 55000
#define NRECMAX (N_NETS + 128)     // nets + macro slots (96 used)
#define NBBLK   129                // ceil(NRECMAX/1024)
#define NPARTS  4
#define BKTCAP  8192               // entries per slab bucket (avg ~4900)
#define STCAP   128                // per-block per-bucket staging (avg ~36)

struct __align__(16) Meta { uint2 cols; float2 whv; float4 pys; };  // 32B

// Per-record deposit data
__device__ uint4 g_pair[NRECMAX * 2];  // {roww(lo16=r0,hi16=r0+1), px0, px1, pad}
__device__ Meta  g_meta[NRECMAX];
__device__ unsigned g_bkt[64 * BKTCAP];              // slab buckets: (i<<1)|pair
__device__ float g_part[NPARTS * 512 * 1024];        // per-part y-scanned tiles

// d_ws layout: u32 bcnt[64] @0; int cnt2[2] @256; int tick @264  (memset to 0)

__global__ __launch_bounds__(1024) void k_bbox(
    const float* __restrict__ pos, const float* __restrict__ pin_pos,
    const float* __restrict__ nsx, const float* __restrict__ nsy,
    const float* __restrict__ nw,  const int* __restrict__ fnp,
    const int* __restrict__ mid, int nm, unsigned* __restrict__ bcnt)
{
    __shared__ unsigned s_stage[64 * STCAP];
    __shared__ int s_cnt[64];
    __shared__ unsigned s_base[64];
    int tid = threadIdx.x;
    int t = blockIdx.x * 1024 + tid;
    if (tid < 64) s_cnt[tid] = 0;
    __syncthreads();

    auto append = [&](int s, unsigned ent) {
        int off = atomicAdd(&s_cnt[s], 1);
        if (off < STCAP) s_stage[s * STCAP + off] = ent;
        else {
            unsigned g = atomicAdd(&bcnt[s], 1u);
            if (g < BKTCAP) g_bkt[s * BKTCAP + g] = ent;
        }
    };

    bool valid = t < N_NETS + nm && t < NRECMAX;
    if (valid) {
        float xmin, xmax, ymin, ymax, wh, wv;
        if (t < N_NETS) {
            int4 p = ((const int4*)fnp)[t];
            float x0 = pin_pos[p.x], x1 = pin_pos[p.y], x2 = pin_pos[p.z], x3 = pin_pos[p.w];
            float y0 = pin_pos[N_PINS + p.x], y1 = pin_pos[N_PINS + p.y];
            float y2 = pin_pos[N_PINS + p.z], y3 = pin_pos[N_PINS + p.w];
            xmin = fminf(fminf(x0, x1), fminf(x2, x3));
            xmax = fmaxf(fmaxf(x0, x1), fmaxf(x2, x3));
            ymin = fminf(fminf(y0, y1), fminf(y2, y3));
            ymax = fmaxf(fmaxf(y0, y1), fmaxf(y2, y3));
            float w = nw[t];
            wh = w / (ymax - ymin);
            wv = w / (xmax - xmin);
        } else {
            int idx = mid[t - N_NETS];
            xmin = pos[idx]; ymin = pos[N_NODES + idx];
            float sx = nsx[idx], sy = nsy[idx];
            xmax = xmin + sx; ymax = ymin + sy;
            wh = wv = 10.0f / (sx * sy);
        }
        const float B = 1.0f / 512.0f;
        int xl = min(max((int)(xmin * 512.0f), 0), 511);
        int xh = min(max((int)(xmax * 512.0f), 0), 511);
        int yl = min(max((int)(ymin * 512.0f), 0), 511);
        int yh = min(max((int)(ymax * 512.0f), 0), 511);
        g_pair[2 * t] = make_uint4(
            (unsigned)xl | ((unsigned)(xl + 1) << 16),
            __float_as_uint((xl + 1) * B - xmin),
            __float_as_uint(xmin - xl * B), 0u);
        g_pair[2 * t + 1] = make_uint4(
            (unsigned)xh | ((unsigned)(xh + 1) << 16),
            __float_as_uint(xmax - (xh + 1) * B),
            __float_as_uint(xh * B - xmax), 0u);
        Meta m;
        m.cols = make_uint2((unsigned)yl | ((unsigned)(yl + 1) << 16),
                            (unsigned)yh | ((unsigned)(yh + 1) << 16));
        m.whv = make_float2(wh, wv);
        m.pys = make_float4((yl + 1) * B - ymin, ymin - yl * B,
                            ymax - (yh + 1) * B, yh * B - ymax);
        g_meta[t] = m;
        int s0 = xl >> 3, s1 = (xl + 1) >> 3, s2 = xh >> 3, s3 = (xh + 1) >> 3;
        append(s0, ((unsigned)t << 1));
        if (s1 != s0 && xl + 1 < 512) append(s1, ((unsigned)t << 1));
        append(s2, ((unsigned)t << 1) | 1u);
        if (s3 != s2 && xh + 1 < 512) append(s3, ((unsigned)t << 1) | 1u);
    }
    __syncthreads();
    if (tid < 64) s_base[tid] = atomicAdd(&bcnt[tid], (unsigned)min(s_cnt[tid], STCAP));
    __syncthreads();
    int wid = tid >> 6, lane = tid & 63;
    for (int s = wid; s < 64; s += 16) {
        int n = min(s_cnt[s], STCAP);
        unsigned b = s_base[s];
        for (int k = lane; k < n; k += 64) {
            unsigned g = b + (unsigned)k;
            if (g < BKTCAP) g_bkt[s * BKTCAP + g] = s_stage[s * STCAP + k];
        }
    }
}

// 256 blocks = 64 slabs x 4 parts. Every entry is a guaranteed deposit:
// no scan, no ballots. Then in-LDS y-scan and exclusive g_part write.
__global__ __launch_bounds__(1024) void k_deposit(const unsigned* __restrict__ bcnt) {
    __shared__ float tile[8706];           // 8 rows x [H 512 | V 512] + dummy @8192
    int tid = threadIdx.x;
    int s = blockIdx.x >> 2, p = blockIdx.x & 3;
    unsigned rowlo = (unsigned)(s * 8);
#pragma unroll
    for (int k = tid; k < 8706; k += 1024) tile[k] = 0.0f;
    __syncthreads();

    int cnt = min((int)bcnt[s], BKTCAP);
    int lo = (cnt * p) >> 2, hi = (cnt * (p + 1)) >> 2;
    for (int k = lo + tid; k < hi; k += 1024) {
        unsigned ent = g_bkt[s * BKTCAP + k];
        int i = (int)(ent >> 1), pr = (int)(ent & 1u);
        uint4 pw = g_pair[2 * i + pr];
        unsigned roww = pw.x;
        float px0 = __uint_as_float(pw.y), px1 = __uint_as_float(pw.z);
        Meta m = g_meta[i];
        unsigned c0 = m.cols.x & 0xFFFFu, c1 = m.cols.x >> 16;
        unsigned c2 = m.cols.y & 0xFFFFu, c3 = m.cols.y >> 16;
        int r0 = (int)(roww & 0xFFFFu);
#pragma unroll
        for (int rr = 0; rr < 2; ++rr) {
            unsigned rel = (unsigned)(r0 + rr) - rowlo;
            if (rel < 8u) {
                float px = rr ? px1 : px0;
                float ah = px * m.whv.x, av = px * m.whv.y;
                int base = (int)rel * 1024;
                int i0 = (c0 < 512u) ? base + (int)c0 : 8192;
                int i1 = (c1 < 512u) ? base + (int)c1 : 8192;
                int i2 = (c2 < 512u) ? base + (int)c2 : 8192;
                int i3 = (c3 < 512u) ? base + (int)c3 : 8192;
                unsafeAtomicAdd(&tile[i0], ah * m.pys.x);
                unsafeAtomicAdd(&tile[i0 + 512], av * m.pys.x);
                unsafeAtomicAdd(&tile[i1], ah * m.pys.y);
                unsafeAtomicAdd(&tile[i1 + 512], av * m.pys.y);
                unsafeAtomicAdd(&tile[i2], ah * m.pys.z);
                unsafeAtomicAdd(&tile[i2 + 512], av * m.pys.z);
                unsafeAtomicAdd(&tile[i3], ah * m.pys.w);
                unsafeAtomicAdd(&tile[i3 + 512], av * m.pys.w);
            }
        }
    }
    __syncthreads();

    // y-scan: wave wid -> (row wid>>1, map wid&1), 8 chunks of 64 with carry
    int wid = tid >> 6, lane = tid & 63;
    {
        int r = wid >> 1, mm = wid & 1;
        int rbase = r * 1024 + mm * 512;
        float carry = 0.0f;
        for (int ch = 0; ch < 8; ++ch) {
            float v = tile[rbase + ch * 64 + lane];
#pragma unroll
            for (int off = 1; off < 64; off <<= 1) {
                float tv = __shfl_up(v, off);
                if (lane >= off) v += tv;
            }
            v += carry;
            tile[rbase + ch * 64 + lane] = v;
            carry = __shfl(v, 63);
        }
    }
    __syncthreads();
    int dst = p * 524288 + (int)rowlo * 1024;
#pragma unroll
    for (int k = 0; k < 8; ++k) {
        int idx = tid + k * 1024;
        g_part[dst + idx] = tile[idx];
    }
}

// 64 blocks, block b owns output cols y in [8b, 8b+8). Part-merge + y-blur
// (shfl) -> LDS; per-wave x-scan + in-register x-blur; map/counts; ticket.
__global__ __launch_bounds__(1024) void k_finish(float* __restrict__ out,
                                                 int* __restrict__ cnt2,
                                                 int* __restrict__ tick) {
    __shared__ float sB[16 * 512];
    int tid = threadIdx.x;
    int b = blockIdx.x;
    int lane = tid & 63;
    int c20 = tid & 31;
    int xg = tid >> 5;
    int jj = (c20 < 10) ? c20 : c20 - 10;
    int cy = 8 * b - 1 + jj;
    if (cy < 0) cy = 1;
    if (cy > 511) cy = 510;
    int gcol = (c20 < 10) ? cy : 512 + cy;
    const float kw  = expf(-0.5f / 1024.0f);
    const float k1n = 1.0f / (1.0f + 2.0f * kw);
    const float k0n = kw * k1n;
    const float scale = 262144.0f / 50000.0f;
    bool active = c20 < 20;
    int t8  = (c20 < 10) ? c20 - 1 : c20 - 11;
    int map = (c20 < 10) ? 0 : 1;

    for (int xo = 0; xo < 16; ++xo) {
        int x = xo * 32 + xg;
        float v = 0.0f;
        if (active) {
            int base = x * 1024 + gcol;
#pragma unroll
            for (int p = 0; p < NPARTS; ++p) v += g_part[p * 524288 + base];
        }
        float vm = __shfl(v, lane - 1);
        float vp = __shfl(v, lane + 1);
        float yb = (k0n * (vm + vp) + k1n * v) * scale;
        if (t8 >= 0 && t8 < 8) sB[(map * 8 + t8) * 512 + x] = yb;
    }
    __syncthreads();

    int w = tid >> 6;
    float s0,s1,s2,s3,s4,s5,s6,s7;
    {
        float4 a  = *(float4*)&sB[w * 512 + lane * 8];
        float4 bq = *(float4*)&sB[w * 512 + lane * 8 + 4];
        s0 = a.x; s1 = s0 + a.y; s2 = s1 + a.z; s3 = s2 + a.w;
        s4 = s3 + bq.x; s5 = s4 + bq.y; s6 = s5 + bq.z; s7 = s6 + bq.w;
        float tot = s7;
#pragma unroll
        for (int off = 1; off < 64; off <<= 1) {
            float tv = __shfl_up(tot, off);
            if (lane >= off) tot += tv;
        }
        float e = tot - s7;
        s0 += e; s1 += e; s2 += e; s3 += e; s4 += e; s5 += e; s6 += e; s7 += e;
    }
    {
        float prev = __shfl(s7, lane - 1);
        float next = __shfl(s0, lane + 1);
        float pm = (lane == 0) ? s1 : prev;
        float nx = (lane == 63) ? s6 : next;
        float b0 = k0n * (pm + s1) + k1n * s0;
        float b1 = k0n * (s0 + s2) + k1n * s1;
        float b2 = k0n * (s1 + s3) + k1n * s2;
        float b3 = k0n * (s2 + s4) + k1n * s3;
        float b4 = k0n * (s3 + s5) + k1n * s4;
        float b5 = k0n * (s4 + s6) + k1n * s5;
        float b6 = k0n * (s5 + s7) + k1n * s6;
        float b7 = k0n * (s6 + nx) + k1n * s7;
        float* row = &sB[w * 512 + lane * 8];
        row[0]=b0; row[1]=b1; row[2]=b2; row[3]=b3;
        row[4]=b4; row[5]=b5; row[6]=b6; row[7]=b7;
    }
    __syncthreads();

    int x = tid >> 1, qh = (tid & 1) * 4;
    float4 o;
    int ch = 0, cv = 0;
#pragma unroll
    for (int k = 0; k < 4; ++k) {
        int tt = qh + k;
        float hv = sB[tt * 512 + x];
        float vv = sB[(8 + tt) * 512 + x];
        ((float*)&o)[k] = fmaxf(fabsf(hv), fabsf(vv));
        ch += (hv > 1.0f); cv += (vv > 1.0f);
    }
    *(float4*)&out[x * 512 + 8 * b + qh] = o;
#pragma unroll
    for (int off = 32; off > 0; off >>= 1) {
        ch += __shfl_down(ch, off);
        cv += __shfl_down(cv, off);
    }
    __shared__ int scnt[2];
    if (tid < 2) scnt[tid] = 0;
    __syncthreads();
    if (lane == 0) { atomicAdd(&scnt[0], ch); atomicAdd(&scnt[1], cv); }
    __syncthreads();
    if (tid == 0) {
        atomicAdd(&cnt2[0], scnt[0]);
        atomicAdd(&cnt2[1], scnt[1]);
        __threadfence();
        int old = atomicAdd(tick, 1);
        if (old == 63) {
            __threadfence();
            int h = cnt2[0], v = cnt2[1];
            out[262144] = (float)((h > v) ? h : v);   // max_overflow
            out[262145] = (float)(h + v);             // total_overflow
        }
    }
}

extern "C" void kernel_launch(void* const* d_in, const int* in_sizes, int n_in,
                              void* d_out, int out_size, void* d_ws, size_t ws_size,
                              hipStream_t stream) {
    const float* pos     = (const float*)d_in[0];
    const float* pin_pos = (const float*)d_in[1];
    const float* nsx     = (const float*)d_in[2];
    const float* nsy     = (const float*)d_in[3];
    const float* nw      = (const float*)d_in[4];
    const int*   fnp     = (const int*)d_in[5];
    const int*   mid     = (const int*)d_in[6];
    int nm = in_sizes[6];
    float* out = (float*)d_out;
    unsigned* bcnt = (unsigned*)d_ws;
    int* cnt2 = (int*)((char*)d_ws + 256);
    int* tick = (int*)((char*)d_ws + 264);

    hipMemsetAsync(d_ws, 0, 512, stream);
    hipLaunchKernelGGL(k_bbox,    dim3(NBBLK), dim3(1024), 0, stream,
                       pos, pin_pos, nsx, nsy, nw, fnp, mid, nm, bcnt);
    hipLaunchKernelGGL(k_deposit, dim3(256), dim3(1024), 0, stream, bcnt);
    hipLaunchKernelGGL(k_finish,  dim3(64), dim3(1024), 0, stream, out, cnt2, tick);
}

// Round 7
// 87.901 us; speedup vs baseline: 4.1072x; 1.0527x over previous
//
#include <hip/hip_runtime.h>

#define N_NETS  131072
#define N_PINS  (N_NETS * 4)
#define N_NODES 55000
#define NRECMAX (N_NETS + 128)     // nets + macro slots (96 used)
#define NBBLK   129                // ceil(NRECMAX/1024)
#define NPARTS  4
#define BKTCAP  16384              // entries per slab bucket (max slab ~8300)
#define STCAP   128                // per-block per-bucket staging (avg ~36)

struct __align__(16) Meta { uint2 cols; float2 whv; float4 pys; };  // 32B

// Per-record deposit data
__device__ uint4 g_pair[NRECMAX * 2];  // {roww(lo16=r0,hi16=r0+1), px0, px1, pad}
__device__ Meta  g_meta[NRECMAX];
__device__ unsigned g_bkt[64 * BKTCAP];              // slab buckets: (i<<1)|pair
__device__ float g_part[NPARTS * 512 * 1024];        // per-part y-scanned tiles
                                                     // layout [p][x][2*y+map]

// d_ws layout: u32 bcnt[64] @0; int cnt2[2] @256; int tick @264  (memset to 0)

__global__ __launch_bounds__(1024) void k_bbox(
    const float* __restrict__ pos, const float* __restrict__ pin_pos,
    const float* __restrict__ nsx, const float* __restrict__ nsy,
    const float* __restrict__ nw,  const int* __restrict__ fnp,
    const int* __restrict__ mid, int nm, unsigned* __restrict__ bcnt)
{
    __shared__ unsigned s_stage[64 * STCAP];
    __shared__ int s_cnt[64];
    __shared__ unsigned s_base[64];
    int tid = threadIdx.x;
    int t = blockIdx.x * 1024 + tid;
    if (tid < 64) s_cnt[tid] = 0;
    __syncthreads();

    auto append = [&](int s, unsigned ent) {
        int off = atomicAdd(&s_cnt[s], 1);
        if (off < STCAP) s_stage[s * STCAP + off] = ent;
        else {
            unsigned g = atomicAdd(&bcnt[s], 1u);
            if (g < BKTCAP) g_bkt[s * BKTCAP + g] = ent;
        }
    };

    bool valid = t < N_NETS + nm && t < NRECMAX;
    if (valid) {
        float xmin, xmax, ymin, ymax, wh, wv;
        if (t < N_NETS) {
            int4 p = ((const int4*)fnp)[t];
            float x0 = pin_pos[p.x], x1 = pin_pos[p.y], x2 = pin_pos[p.z], x3 = pin_pos[p.w];
            float y0 = pin_pos[N_PINS + p.x], y1 = pin_pos[N_PINS + p.y];
            float y2 = pin_pos[N_PINS + p.z], y3 = pin_pos[N_PINS + p.w];
            xmin = fminf(fminf(x0, x1), fminf(x2, x3));
            xmax = fmaxf(fmaxf(x0, x1), fmaxf(x2, x3));
            ymin = fminf(fminf(y0, y1), fminf(y2, y3));
            ymax = fmaxf(fmaxf(y0, y1), fmaxf(y2, y3));
            float w = nw[t];
            wh = w / (ymax - ymin);
            wv = w / (xmax - xmin);
        } else {
            int idx = mid[t - N_NETS];
            xmin = pos[idx]; ymin = pos[N_NODES + idx];
            float sx = nsx[idx], sy = nsy[idx];
            xmax = xmin + sx; ymax = ymin + sy;
            wh = wv = 10.0f / (sx * sy);
        }
        const float B = 1.0f / 512.0f;
        int xl = min(max((int)(xmin * 512.0f), 0), 511);
        int xh = min(max((int)(xmax * 512.0f), 0), 511);
        int yl = min(max((int)(ymin * 512.0f), 0), 511);
        int yh = min(max((int)(ymax * 512.0f), 0), 511);
        g_pair[2 * t] = make_uint4(
            (unsigned)xl | ((unsigned)(xl + 1) << 16),
            __float_as_uint((xl + 1) * B - xmin),
            __float_as_uint(xmin - xl * B), 0u);
        g_pair[2 * t + 1] = make_uint4(
            (unsigned)xh | ((unsigned)(xh + 1) << 16),
            __float_as_uint(xmax - (xh + 1) * B),
            __float_as_uint(xh * B - xmax), 0u);
        Meta m;
        m.cols = make_uint2((unsigned)yl | ((unsigned)(yl + 1) << 16),
                            (unsigned)yh | ((unsigned)(yh + 1) << 16));
        m.whv = make_float2(wh, wv);
        m.pys = make_float4((yl + 1) * B - ymin, ymin - yl * B,
                            ymax - (yh + 1) * B, yh * B - ymax);
        g_meta[t] = m;
        int s0 = xl >> 3, s1 = (xl + 1) >> 3, s2 = xh >> 3, s3 = (xh + 1) >> 3;
        append(s0, ((unsigned)t << 1));
        if (s1 != s0 && xl + 1 < 512) append(s1, ((unsigned)t << 1));
        append(s2, ((unsigned)t << 1) | 1u);
        if (s3 != s2 && xh + 1 < 512) append(s3, ((unsigned)t << 1) | 1u);
    }
    __syncthreads();
    if (tid < 64) s_base[tid] = atomicAdd(&bcnt[tid], (unsigned)min(s_cnt[tid], STCAP));
    __syncthreads();
    int wid = tid >> 6, lane = tid & 63;
    for (int s = wid; s < 64; s += 16) {
        int n = min(s_cnt[s], STCAP);
        unsigned b = s_base[s];
        for (int k = lane; k < n; k += 64) {
            unsigned g = b + (unsigned)k;
            if (g < BKTCAP) g_bkt[s * BKTCAP + g] = s_stage[s * STCAP + k];
        }
    }
}

// 256 blocks = 64 slabs x 4 parts. Interleaved tile [row][2*col+map]:
// H,V of each point hit ADJACENT banks (old layout: +512 floats = same bank).
__global__ __launch_bounds__(1024) void k_deposit(const unsigned* __restrict__ bcnt) {
    __shared__ float tile[8706];           // 8 rows x 1024 interleaved + dummy @8192
    int tid = threadIdx.x;
    int s = blockIdx.x >> 2, p = blockIdx.x & 3;
    unsigned rowlo = (unsigned)(s * 8);
#pragma unroll
    for (int k = tid; k < 8706; k += 1024) tile[k] = 0.0f;
    __syncthreads();

    int cnt = min((int)bcnt[s], BKTCAP);
    int lo = (cnt * p) >> 2, hi = (cnt * (p + 1)) >> 2;
    for (int k = lo + tid; k < hi; k += 1024) {
        unsigned ent = g_bkt[s * BKTCAP + k];
        int i = (int)(ent >> 1), pr = (int)(ent & 1u);
        uint4 pw = g_pair[2 * i + pr];
        unsigned roww = pw.x;
        float px0 = __uint_as_float(pw.y), px1 = __uint_as_float(pw.z);
        Meta m = g_meta[i];
        unsigned c0 = m.cols.x & 0xFFFFu, c1 = m.cols.x >> 16;
        unsigned c2 = m.cols.y & 0xFFFFu, c3 = m.cols.y >> 16;
        int r0 = (int)(roww & 0xFFFFu);
#pragma unroll
        for (int rr = 0; rr < 2; ++rr) {
            unsigned rel = (unsigned)(r0 + rr) - rowlo;
            if (rel < 8u) {
                float px = rr ? px1 : px0;
                float ah = px * m.whv.x, av = px * m.whv.y;
                int base = (int)rel * 1024;
                int i0 = (c0 < 512u) ? base + 2 * (int)c0 : 8192;
                int i1 = (c1 < 512u) ? base + 2 * (int)c1 : 8192;
                int i2 = (c2 < 512u) ? base + 2 * (int)c2 : 8192;
                int i3 = (c3 < 512u) ? base + 2 * (int)c3 : 8192;
                unsafeAtomicAdd(&tile[i0],     ah * m.pys.x);
                unsafeAtomicAdd(&tile[i0 + 1], av * m.pys.x);
                unsafeAtomicAdd(&tile[i1],     ah * m.pys.y);
                unsafeAtomicAdd(&tile[i1 + 1], av * m.pys.y);
                unsafeAtomicAdd(&tile[i2],     ah * m.pys.z);
                unsafeAtomicAdd(&tile[i2 + 1], av * m.pys.z);
                unsafeAtomicAdd(&tile[i3],     ah * m.pys.w);
                unsafeAtomicAdd(&tile[i3 + 1], av * m.pys.w);
            }
        }
    }
    __syncthreads();

    // y-scan: 8 waves, wave r scans row r as float2 (H,V together, ds_read_b64
    // conflict-free), 8 chunks of 64 with carry
    int wid = tid >> 6, lane = tid & 63;
    if (wid < 8) {
        float2* rowp = (float2*)&tile[wid * 1024];
        float cx = 0.0f, cy = 0.0f;
        for (int ch = 0; ch < 8; ++ch) {
            float2 v = rowp[ch * 64 + lane];
#pragma unroll
            for (int off = 1; off < 64; off <<= 1) {
                float tx = __shfl_up(v.x, off);
                float ty = __shfl_up(v.y, off);
                if (lane >= off) { v.x += tx; v.y += ty; }
            }
            v.x += cx; v.y += cy;
            rowp[ch * 64 + lane] = v;
            cx = __shfl(v.x, 63); cy = __shfl(v.y, 63);
        }
    }
    __syncthreads();
    int dst = p * 524288 + (int)rowlo * 1024;
#pragma unroll
    for (int k = 0; k < 8; ++k) {
        int idx = tid + k * 1024;
        g_part[dst + idx] = tile[idx];
    }
}

// 64 blocks, block b owns output cols y in [8b, 8b+8). Part-merge + y-blur
// (shfl) -> LDS; per-wave x-scan + in-register x-blur; map/counts; ticket.
__global__ __launch_bounds__(1024) void k_finish(float* __restrict__ out,
                                                 int* __restrict__ cnt2,
                                                 int* __restrict__ tick) {
    __shared__ float sB[16 * 512];
    int tid = threadIdx.x;
    int b = blockIdx.x;
    int lane = tid & 63;
    int c20 = tid & 31;
    int xg = tid >> 5;
    int jj = (c20 < 10) ? c20 : c20 - 10;
    int cy = 8 * b - 1 + jj;
    if (cy < 0) cy = 1;
    if (cy > 511) cy = 510;
    int map = (c20 < 10) ? 0 : 1;
    int gcol = 2 * cy + map;                // interleaved column
    const float kw  = expf(-0.5f / 1024.0f);
    const float k1n = 1.0f / (1.0f + 2.0f * kw);
    const float k0n = kw * k1n;
    const float scale = 262144.0f / 50000.0f;
    bool active = c20 < 20;
    int t8  = (c20 < 10) ? c20 - 1 : c20 - 11;

    for (int xo = 0; xo < 16; ++xo) {
        int x = xo * 32 + xg;
        float v = 0.0f;
        if (active) {
            int base = x * 1024 + gcol;
#pragma unroll
            for (int p = 0; p < NPARTS; ++p) v += g_part[p * 524288 + base];
        }
        float vm = __shfl(v, lane - 1);
        float vp = __shfl(v, lane + 1);
        float yb = (k0n * (vm + vp) + k1n * v) * scale;
        if (t8 >= 0 && t8 < 8) sB[(map * 8 + t8) * 512 + x] = yb;
    }
    __syncthreads();

    int w = tid >> 6;
    float s0,s1,s2,s3,s4,s5,s6,s7;
    {
        float4 a  = *(float4*)&sB[w * 512 + lane * 8];
        float4 bq = *(float4*)&sB[w * 512 + lane * 8 + 4];
        s0 = a.x; s1 = s0 + a.y; s2 = s1 + a.z; s3 = s2 + a.w;
        s4 = s3 + bq.x; s5 = s4 + bq.y; s6 = s5 + bq.z; s7 = s6 + bq.w;
        float tot = s7;
#pragma unroll
        for (int off = 1; off < 64; off <<= 1) {
            float tv = __shfl_up(tot, off);
            if (lane >= off) tot += tv;
        }
        float e = tot - s7;
        s0 += e; s1 += e; s2 += e; s3 += e; s4 += e; s5 += e; s6 += e; s7 += e;
    }
    {
        float prev = __shfl(s7, lane - 1);
        float next = __shfl(s0, lane + 1);
        float pm = (lane == 0) ? s1 : prev;
        float nx = (lane == 63) ? s6 : next;
        float b0 = k0n * (pm + s1) + k1n * s0;
        float b1 = k0n * (s0 + s2) + k1n * s1;
        float b2 = k0n * (s1 + s3) + k1n * s2;
        float b3 = k0n * (s2 + s4) + k1n * s3;
        float b4 = k0n * (s3 + s5) + k1n * s4;
        float b5 = k0n * (s4 + s6) + k1n * s5;
        float b6 = k0n * (s5 + s7) + k1n * s6;
        float b7 = k0n * (s6 + nx) + k1n * s7;
        float* row = &sB[w * 512 + lane * 8];
        row[0]=b0; row[1]=b1; row[2]=b2; row[3]=b3;
        row[4]=b4; row[5]=b5; row[6]=b6; row[7]=b7;
    }
    __syncthreads();

    int x = tid >> 1, qh = (tid & 1) * 4;
    float4 o;
    int ch = 0, cv = 0;
#pragma unroll
    for (int k = 0; k < 4; ++k) {
        int tt = qh + k;
        float hv = sB[tt * 512 + x];
        float vv = sB[(8 + tt) * 512 + x];
        ((float*)&o)[k] = fmaxf(fabsf(hv), fabsf(vv));
        ch += (hv > 1.0f); cv += (vv > 1.0f);
    }
    *(float4*)&out[x * 512 + 8 * b + qh] = o;
#pragma unroll
    for (int off = 32; off > 0; off >>= 1) {
        ch += __shfl_down(ch, off);
        cv += __shfl_down(cv, off);
    }
    __shared__ int scnt[2];
    if (tid < 2) scnt[tid] = 0;
    __syncthreads();
    if (lane == 0) { atomicAdd(&scnt[0], ch); atomicAdd(&scnt[1], cv); }
    __syncthreads();
    if (tid == 0) {
        atomicAdd(&cnt2[0], scnt[0]);
        atomicAdd(&cnt2[1], scnt[1]);
        __threadfence();
        int old = atomicAdd(tick, 1);
        if (old == 63) {
            __threadfence();
            int h = cnt2[0], v = cnt2[1];
            out[262144] = (float)((h > v) ? h : v);   // max_overflow
            out[262145] = (float)(h + v);             // total_overflow
        }
    }
}

extern "C" void kernel_launch(void* const* d_in, const int* in_sizes, int n_in,
                              void* d_out, int out_size, void* d_ws, size_t ws_size,
                              hipStream_t stream) {
    const float* pos     = (const float*)d_in[0];
    const float* pin_pos = (const float*)d_in[1];
    const float* nsx     = (const float*)d_in[2];
    const float* nsy     = (const float*)d_in[3];
    const float* nw      = (const float*)d_in[4];
    const int*   fnp     = (const int*)d_in[5];
    const int*   mid     = (const int*)d_in[6];
    int nm = in_sizes[6];
    float* out = (float*)d_out;
    unsigned* bcnt = (unsigned*)d_ws;
    int* cnt2 = (int*)((char*)d_ws + 256);
    int* tick = (int*)((char*)d_ws + 264);

    hipMemsetAsync(d_ws, 0, 512, stream);
    hipLaunchKernelGGL(k_bbox,    dim3(NBBLK), dim3(1024), 0, stream,
                       pos, pin_pos, nsx, nsy, nw, fnp, mid, nm, bcnt);
    hipLaunchKernelGGL(k_deposit, dim3(256), dim3(1024), 0, stream, bcnt);
    hipLaunchKernelGGL(k_finish,  dim3(64), dim3(1024), 0, stream, out, cnt2, tick);
}